// Round 1
// baseline (65.664 us; speedup 1.0000x reference)
//
#include <hip/hip_runtime.h>

// Reference reduces to:
//   u  = embed_user[user]            [B,128]
//   it = embed_item[item]            [B,128]
//   predict = sum(u*it,-1)*0.7 + average + user_bias[user] + item_bias[item]
// kmeans() result is multiplied into cluster_pred=0.0 constant -> dead code.
// Output layout (flat f32): predict[B] | u[B*128] | it[B*128].

__global__ __launch_bounds__(256) void cbmf_gather_dot(
    const int* __restrict__ user,
    const int* __restrict__ item,
    const float* __restrict__ average,
    const float* __restrict__ embed_user,
    const float* __restrict__ embed_item,
    const float* __restrict__ user_bias,
    const float* __restrict__ item_bias,
    float* __restrict__ out_pred,
    float* __restrict__ out_u,
    float* __restrict__ out_it,
    int B)
{
    // one 64-lane wave per batch row; 4 waves per 256-thread block
    const int row  = (blockIdx.x << 2) + (threadIdx.x >> 6);
    const int lane = threadIdx.x & 63;
    if (row >= B) return;

    const int uidx = user[row];
    const int iidx = item[row];

    const float2* __restrict__ urow = (const float2*)(embed_user + (size_t)uidx * 128);
    const float2* __restrict__ irow = (const float2*)(embed_item + (size_t)iidx * 128);

    const float2 uv = urow[lane];
    const float2 iv = irow[lane];

    ((float2*)(out_u  + (size_t)row * 128))[lane] = uv;
    ((float2*)(out_it + (size_t)row * 128))[lane] = iv;

    float dot = uv.x * iv.x + uv.y * iv.y;
    #pragma unroll
    for (int off = 32; off > 0; off >>= 1)
        dot += __shfl_down(dot, off, 64);

    if (lane == 0) {
        out_pred[row] = dot * 0.7f + average[0] + user_bias[uidx] + item_bias[iidx];
    }
}

extern "C" void kernel_launch(void* const* d_in, const int* in_sizes, int n_in,
                              void* d_out, int out_size, void* d_ws, size_t ws_size,
                              hipStream_t stream) {
    const int*   user       = (const int*)d_in[0];
    const int*   item       = (const int*)d_in[1];
    const float* average    = (const float*)d_in[2];
    const float* embed_user = (const float*)d_in[3];
    const float* embed_item = (const float*)d_in[4];
    const float* user_bias  = (const float*)d_in[5];
    const float* item_bias  = (const float*)d_in[6];

    const int B = in_sizes[0];

    float* out_pred = (float*)d_out;
    float* out_u    = out_pred + B;
    float* out_it   = out_u + (size_t)B * 128;

    const int blocks = (B + 3) / 4;  // 4 rows (waves) per block
    cbmf_gather_dot<<<blocks, 256, 0, stream>>>(
        user, item, average, embed_user, embed_item, user_bias, item_bias,
        out_pred, out_u, out_it, B);
}

// Round 2
// 49.735 us; speedup vs baseline: 1.3203x; 1.3203x over previous
//
#include <hip/hip_runtime.h>

// Reference reduces to:
//   u  = embed_user[user]            [B,128]
//   it = embed_item[item]            [B,128]
//   predict = sum(u*it,-1)*0.7 + average + user_bias[user] + item_bias[item]
// kmeans() is dead code (cluster_pred = 0.0 constant).
// Output layout (flat f32): predict[B] | u[B*128] | it[B*128].
//
// Layout: 256-thread block = 4 waves; each wave handles 4 rows (two halves
// of 32 lanes x 2 unrolled row-pairs). 16 B/lane float4 loads; NT stores.

typedef float f32x4 __attribute__((ext_vector_type(4)));

__global__ __launch_bounds__(256) void cbmf_gather_dot(
    const int* __restrict__ user,
    const int* __restrict__ item,
    const float* __restrict__ average,
    const float* __restrict__ embed_user,
    const float* __restrict__ embed_item,
    const float* __restrict__ user_bias,
    const float* __restrict__ item_bias,
    float* __restrict__ out_pred,
    float* __restrict__ out_u,
    float* __restrict__ out_it,
    int B)
{
    const int wave = threadIdx.x >> 6;      // 0..3
    const int lane = threadIdx.x & 63;
    const int half = lane >> 5;             // 0 or 1: which row of the pair
    const int l32  = lane & 31;             // 32 lanes x 16 B = 512 B row

    const int base = (blockIdx.x << 4) + (wave << 2);  // 16 rows/block
    const int rowA = base + half;
    const int rowB = base + 2 + half;
    if (rowA >= B) return;
    const bool hasB = (rowB < B);

    // indices first (both rows) so all 4 embedding gathers can be in flight
    const int uA = user[rowA];
    const int iA = item[rowA];
    const int uB = hasB ? user[rowB] : uA;
    const int iB = hasB ? item[rowB] : iA;

    const f32x4 ua = ((const f32x4*)(embed_user + (size_t)uA * 128))[l32];
    const f32x4 va = ((const f32x4*)(embed_item + (size_t)iA * 128))[l32];
    const f32x4 ub = ((const f32x4*)(embed_user + (size_t)uB * 128))[l32];
    const f32x4 vb = ((const f32x4*)(embed_item + (size_t)iB * 128))[l32];

    // streaming outputs -> nontemporal (no reuse; keep L2/L3 for gathers)
    __builtin_nontemporal_store(ua, ((f32x4*)(out_u  + (size_t)rowA * 128)) + l32);
    __builtin_nontemporal_store(va, ((f32x4*)(out_it + (size_t)rowA * 128)) + l32);
    if (hasB) {
        __builtin_nontemporal_store(ub, ((f32x4*)(out_u  + (size_t)rowB * 128)) + l32);
        __builtin_nontemporal_store(vb, ((f32x4*)(out_it + (size_t)rowB * 128)) + l32);
    }

    float dotA = ua[0]*va[0] + ua[1]*va[1] + ua[2]*va[2] + ua[3]*va[3];
    float dotB = ub[0]*vb[0] + ub[1]*vb[1] + ub[2]*vb[2] + ub[3]*vb[3];

    #pragma unroll
    for (int off = 16; off > 0; off >>= 1) {
        dotA += __shfl_down(dotA, off, 32);
        dotB += __shfl_down(dotB, off, 32);
    }

    if (l32 == 0) {
        const float avg = average[0];
        out_pred[rowA] = dotA * 0.7f + avg + user_bias[uA] + item_bias[iA];
        if (hasB)
            out_pred[rowB] = dotB * 0.7f + avg + user_bias[uB] + item_bias[iB];
    }
}

extern "C" void kernel_launch(void* const* d_in, const int* in_sizes, int n_in,
                              void* d_out, int out_size, void* d_ws, size_t ws_size,
                              hipStream_t stream) {
    const int*   user       = (const int*)d_in[0];
    const int*   item       = (const int*)d_in[1];
    const float* average    = (const float*)d_in[2];
    const float* embed_user = (const float*)d_in[3];
    const float* embed_item = (const float*)d_in[4];
    const float* user_bias  = (const float*)d_in[5];
    const float* item_bias  = (const float*)d_in[6];

    const int B = in_sizes[0];

    float* out_pred = (float*)d_out;
    float* out_u    = out_pred + B;
    float* out_it   = out_u + (size_t)B * 128;

    const int blocks = (B + 15) / 16;  // 16 rows per 256-thread block
    cbmf_gather_dot<<<blocks, 256, 0, stream>>>(
        user, item, average, embed_user, embed_item, user_bias, item_bias,
        out_pred, out_u, out_it, B);
}